// Round 12
// baseline (2777.515 us; speedup 1.0000x reference)
//
#include <hip/hip_runtime.h>
#include <math.h>

typedef float f4 __attribute__((ext_vector_type(4)));
typedef short bf16x8 __attribute__((ext_vector_type(8)));
typedef unsigned u32x2 __attribute__((ext_vector_type(2)));
typedef unsigned u32x4 __attribute__((ext_vector_type(4)));

#define NT 512

// ---- ws dword offsets ----
#define H0R 0            // 4 ring slots x (hi 16384 dw + lo 16384 dw)
#define H1R 131072       // 2 slots x 32768 dw
#define PLOG 196608      // 64*64 floats
#define FLAGS 200704     // flag0: 64 lines x 32 dw (dw 0,1 used); flag1 at +2048
#define WSW 204800       // 8 regions x 131072 f4 (16 MB)
#define XBF 4399104      // 512 t x 128 chunk x 32 b f4 (32 MB)

__device__ __forceinline__ unsigned pack_bf16(float lo, float hi) {
  unsigned u;
  asm volatile("v_cvt_pk_bf16_f32 %0, %1, %2" : "=v"(u) : "v"(lo), "v"(hi));
  return u;
}
__device__ __forceinline__ float bflo(unsigned d) { return __uint_as_float(d << 16); }
__device__ __forceinline__ float bfhi(unsigned d) { return __uint_as_float(d & 0xffff0000u); }
__device__ __forceinline__ void st_cohf(float* p, float v) {
  __hip_atomic_store(p, v, __ATOMIC_RELAXED, __HIP_MEMORY_SCOPE_AGENT);
}
__device__ __forceinline__ void st_cohu(unsigned* p, unsigned v) {
  __hip_atomic_store(p, v, __ATOMIC_RELAXED, __HIP_MEMORY_SCOPE_AGENT);
}
__device__ __forceinline__ unsigned long long ld64(const unsigned long long* p) {
  return __hip_atomic_load(p, __ATOMIC_RELAXED, __HIP_MEMORY_SCOPE_AGENT);
}

__device__ __forceinline__ void split8(const f4 v0, const f4 v1, u32x4& hi, u32x4& lo) {
  float h_[8] = {v0[0], v0[1], v0[2], v0[3], v1[0], v1[1], v1[2], v1[3]};
  #pragma unroll
  for (int e = 0; e < 4; ++e) hi[e] = pack_bf16(h_[2*e], h_[2*e+1]);
  float r[8];
  #pragma unroll
  for (int e = 0; e < 4; ++e) {
    r[2*e]   = h_[2*e]   - bflo(hi[e]);
    r[2*e+1] = h_[2*e+1] - bfhi(hi[e]);
  }
  #pragma unroll
  for (int e = 0; e < 4; ++e) lo[e] = pack_bf16(r[2*e], r[2*e+1]);
}

// W fp32 row-major -> WSW[(mat*2+part)] swizzled bf16 hi/lo
// mat order: 0=Whh0, 1=Wih0, 2=Wih1, 3=Whh1
__global__ __launch_bounds__(128) void wconv_kernel(
    const float* __restrict__ W0, const float* __restrict__ W1,
    const float* __restrict__ W2, const float* __restrict__ W3,
    float* __restrict__ ws) {
  const int mat = blockIdx.x >> 10;
  const int j = blockIdx.x & 1023;
  const int kc = threadIdx.x;
  const float* Wm = (mat == 0) ? W0 : (mat == 1) ? W1 : (mat == 2) ? W2 : W3;
  const f4* src = (const f4*)(Wm + (size_t)j * 1024 + kc * 8);
  f4 v0 = src[0], v1 = src[1];
  u32x4 hi, lo;
  split8(v0, v1, hi, lo);
  u32x4* dst = (u32x4*)((f4*)ws + (WSW >> 2));
  size_t base = (size_t)(mat * 2) * 131072 + (j >> 4) * 2048 + kc * 16 + (j & 15);
  dst[base] = hi;
  dst[base + 131072] = lo;
}

// x[b][t][k] fp32 -> XBF[t][chunk][b] single-bf16
__global__ __launch_bounds__(128) void xconv_kernel(const float* __restrict__ x,
                                                    float* __restrict__ ws) {
  const int t = blockIdx.x;
  const int kc = threadIdx.x;
  u32x4* dst = (u32x4*)((f4*)ws + (XBF >> 2)) + (size_t)t * 4096;
  for (int b = 0; b < 32; ++b) {
    const f4* src = (const f4*)(x + ((size_t)b * NT + t) * 1024 + kc * 8);
    f4 v0 = src[0], v1 = src[1];
    u32x4 p;
    #pragma unroll
    for (int e = 0; e < 4; ++e)
      p[e] = pack_bf16(e < 2 ? v0[2*e] : v1[2*e-4], e < 2 ? v0[2*e+1] : v1[2*e-3]);
    dst[(size_t)kc * 32 + b] = p;
  }
}

// h0 init: layer0 -> H0R slot 3 (h0(-1)); layer1 -> H1R slot 1 (h1(-1)); zero flags
__global__ __launch_bounds__(256) void hinit_kernel(const float* __restrict__ h0,
                                                    float* __restrict__ ws) {
  int g = blockIdx.x * 256 + threadIdx.x;  // 0..8191
  int l = g >> 12, b = (g >> 7) & 31, kc = g & 127;
  const f4* src = (const f4*)(h0 + (size_t)l * 32768 + b * 1024 + kc * 8);
  f4 v0 = src[0], v1 = src[1];
  u32x4 hi, lo;
  split8(v0, v1, hi, lo);
  unsigned base = l ? (H1R + 32768) : (H0R + 3 * 32768);
  u32x4* d = (u32x4*)((unsigned*)ws + base);
  d[(size_t)kc * 32 + b] = hi;
  d[4096 + (size_t)kc * 32 + b] = lo;
  if (g < 4096) ((unsigned*)ws)[FLAGS + g] = 0u;
}

#define LDG(dst, ptr) \
  asm volatile("global_load_dwordx4 %0, %1, off sc0" : "=v"(dst) : "v"(ptr))
#define LDP(dst, ptr) \
  asm volatile("global_load_dwordx4 %0, %1, off" : "=v"(dst) : "v"(ptr))
#define STG2(ptr, val) \
  asm volatile("global_store_dwordx2 %0, %1, off sc0 sc1" ::"v"(ptr), "v"(val) : "memory")
#define MFMA(a, b, c) __builtin_amdgcn_mfma_f32_16x16x32_bf16(a, b, c, 0, 0, 0)
#define BC(v) __builtin_bit_cast(bf16x8, v)

// rolling 16-pair register file: pair p -> bh[p&15], bl[p&15]
#define ISSM(p) LDG(bh[(p) & 15], ph + (p) * 128); LDG(bl[(p) & 15], pl + (p) * 128);
#define ISS_A ISSM(0) ISSM(1) ISSM(2) ISSM(3) ISSM(4) ISSM(5) ISSM(6) ISSM(7) \
  ISSM(8) ISSM(9) ISSM(10) ISSM(11) ISSM(12) ISSM(13) ISSM(14) ISSM(15)

// main: W slots 0(hi)/1(lo) x h hi/lo, 3 MFMA per 32-k window
#define KT_M(m, N)                                                        \
  asm volatile("s_waitcnt vmcnt(" #N ")");                                \
  __builtin_amdgcn_sched_barrier(0xF4);                                   \
  {                                                                       \
    const int ci = ((kg + (m) * 4) << 4) + jl;                            \
    bf16x8 a0 = w4b[ci], a1 = w4b[2048 + ci];                             \
    bf16x8 vh = BC(bh[(m) & 15]), vl = BC(bl[(m) & 15]);                  \
    cr = MFMA(a0, vh, cr); cr = MFMA(a0, vl, cr); cr = MFMA(a1, vh, cr);  \
  }
// L1 tail: W slots 2(hi)/3(lo) x h0 hi/lo
#define KT_G(m, N)                                                        \
  asm volatile("s_waitcnt vmcnt(" #N ")");                                \
  __builtin_amdgcn_sched_barrier(0xF4);                                   \
  {                                                                       \
    const int ci = ((kg + (m) * 4) << 4) + jl;                            \
    bf16x8 a2 = w4b[4096 + ci], a3 = w4b[6144 + ci];                      \
    bf16x8 vh = BC(bh[(m) & 15]), vl = BC(bl[(m) & 15]);                  \
    cp = MFMA(a2, vh, cp); cp = MFMA(a2, vl, cp); cp = MFMA(a3, vh, cp);  \
  }
// L0 tail: W slot 2 (Wih0_hi) x x
#define KT_X(m, N)                                                        \
  asm volatile("s_waitcnt vmcnt(" #N ")");                                \
  __builtin_amdgcn_sched_barrier(0xF4);                                   \
  {                                                                       \
    const int ci = ((kg + (m) * 4) << 4) + jl;                            \
    bf16x8 a2 = w4b[4096 + ci];                                           \
    cp = MFMA(a2, BC(bx[m]), cp);                                         \
  }

// full-K pipeline: issue 32, steady-state 1-consume/1-issue at vmcnt(30), drain
#define PIPE(KT)                                                          \
  ISS_A                                                                   \
  KT(0,30)  ISSM(16) KT(1,30)  ISSM(17) KT(2,30)  ISSM(18) KT(3,30)  ISSM(19) \
  KT(4,30)  ISSM(20) KT(5,30)  ISSM(21) KT(6,30)  ISSM(22) KT(7,30)  ISSM(23) \
  KT(8,30)  ISSM(24) KT(9,30)  ISSM(25) KT(10,30) ISSM(26) KT(11,30) ISSM(27) \
  KT(12,30) ISSM(28) KT(13,30) ISSM(29) KT(14,30) ISSM(30) KT(15,30) ISSM(31) \
  KT(16,30) KT(17,28) KT(18,26) KT(19,24) KT(20,22) KT(21,20) KT(22,18)   \
  KT(23,16) KT(24,14) KT(25,12) KT(26,10) KT(27,8) KT(28,6) KT(29,4)      \
  KT(30,2)  KT(31,0)

#define REP32(F) F(0) F(1) F(2) F(3) F(4) F(5) F(6) F(7) F(8) F(9) F(10) F(11) \
  F(12) F(13) F(14) F(15) F(16) F(17) F(18) F(19) F(20) F(21) F(22) F(23) \
  F(24) F(25) F(26) F(27) F(28) F(29) F(30) F(31)
#define LDXM(m) LDP(bx[m], px + (m) * 128);
#define KTXLIST(KT) KT(0,31) KT(1,30) KT(2,29) KT(3,28) KT(4,27) KT(5,26) \
  KT(6,25) KT(7,24) KT(8,23) KT(9,22) KT(10,21) KT(11,20) KT(12,19) KT(13,18) \
  KT(14,17) KT(15,16) KT(16,15) KT(17,14) KT(18,13) KT(19,12) KT(20,11) \
  KT(21,10) KT(22,9) KT(23,8) KT(24,7) KT(25,6) KT(26,5) KT(27,4) KT(28,3) \
  KT(29,2) KT(30,1) KT(31,0)

// flag line accessors: line l is at 32-dword (128 B) stride
#define F0L(lx) ((const unsigned long long*)(flg + (lx) * 32))
#define F1L(lx) ((const unsigned long long*)(flg + 2048 + (lx) * 32))

// 128 blocks x 256 threads (4 waves). bid<64: L0 {Whh0, Wih0}; bid>=64: L1.
// Waves 0-1: full-K main GEMM + tanh + store + per-wave flag publish.
// Waves 2-3: next-step input projection into LDS prebuf.
__global__ __launch_bounds__(256, 1) void rnn_kernel(
    const float* __restrict__ bih0, const float* __restrict__ bhh0,
    const float* __restrict__ bih1, const float* __restrict__ bhh1,
    const float* __restrict__ Wcls, const float* __restrict__ bcls,
    float* __restrict__ out, float* ws) {
  extern __shared__ float smem[];
  f4* w4 = (f4*)smem;                 // 8192 f4 = 128 KB (4 slots x 2048)
  bf16x8* w4b = (bf16x8*)smem;
  float* prebuf = smem + 32768;       // [2][16][33] f32
  float* lgred = prebuf;              // epilogue reuse

  const int bid = blockIdx.x, tid = threadIdx.x;
  const bool isL1 = bid >= 64;
  const int jsl = bid & 63;
  const int w = tid >> 6, l = tid & 63;
  const int jl = l & 15, kg = l >> 4;
  const int nt = w & 1;
  const int bcol = nt * 16 + jl;      // B col (b) for loads AND D col
  const int j0 = kg * 4;              // D rows j0..j0+3
  const int jcol0 = jsl * 16 + j0;

  unsigned* flg = (unsigned*)ws + FLAGS;
  const f4* wsf4 = (const f4*)ws;

  // ---- stage weights into LDS ----
  {
    const int nent = isL1 ? 8192 : 6144;
    for (int i = tid; i < nent; i += 256) {
      const int slot = i >> 11, idx = i & 2047;
      const int region = isL1 ? (slot < 2 ? 6 + slot : 2 + slot) : slot;
      w4[i] = wsf4[(WSW >> 2) + (size_t)region * 131072 + jsl * 2048 + idx];
    }
  }
  f4 biasv = (f4)0.f;
  if (w < 2) {
    f4 bi = isL1 ? *(const f4*)(bih1 + jcol0) : *(const f4*)(bih0 + jcol0);
    f4 bh2 = isL1 ? *(const f4*)(bhh1 + jcol0) : *(const f4*)(bhh0 + jcol0);
    biasv = bi + bh2;
  }
  float lg0 = 0.f, lg1 = 0.f;
  __syncthreads();

  if (!isL1) {
    // ===================== L0 =====================
    for (int s = -1; s < NT; ++s) {
      if (w < 2) {
        if (s >= 0) {
          {  // poll: all flag0 >= s; ring guard: all flag1 >= s-3
            const unsigned long long* p0 = F0L(l);
            const unsigned long long* p1 = F1L(l);
            const int b1 = s - 3;
            while (true) {
              unsigned long long v0 = ld64(p0);
              unsigned long long v1 = ld64(p1);
              if ((int)(unsigned)v0 >= s && (int)(unsigned)(v0 >> 32) >= s &&
                  (int)(unsigned)v1 >= b1 && (int)(unsigned)(v1 >> 32) >= b1)
                break;
            }
          }
          __builtin_amdgcn_sched_barrier(0);
          const f4* ph = wsf4 + ((s + 3) & 3) * 8192 + kg * 32 + bcol;  // h0(s-1)
          const f4* pl = ph + 4096;
          f4 bh[16], bl[16];
          f4 cr = (f4)0.f;
          PIPE(KT_M)
          const int pp = s & 1;
          float h_[4];
          #pragma unroll
          for (int e = 0; e < 4; ++e)
            h_[e] = tanhf(cr[e] + biasv[e] +
                          prebuf[pp * 528 + (j0 + e) * 33 + bcol]);
          unsigned hi0 = pack_bf16(h_[0], h_[1]), hi1 = pack_bf16(h_[2], h_[3]);
          unsigned lo0 = pack_bf16(h_[0] - bflo(hi0), h_[1] - bfhi(hi0));
          unsigned lo1 = pack_bf16(h_[2] - bflo(hi1), h_[3] - bfhi(hi1));
          u32x2 hp; hp[0] = hi0; hp[1] = hi1;
          u32x2 lp; lp[0] = lo0; lp[1] = lo1;
          unsigned* dp = (unsigned*)ws + H0R + (s & 3) * 32768 +
                         ((jcol0 >> 3) * 32 + bcol) * 4 + ((jcol0 >> 1) & 3);
          STG2(dp, hp);
          STG2(dp + 16384, lp);
          if (s == NT - 1) {
            f4 o; o[0] = h_[0]; o[1] = h_[1]; o[2] = h_[2]; o[3] = h_[3];
            *(f4*)(out + 64 + (size_t)bcol * 1024 + jcol0) = o;
          }
          asm volatile("s_waitcnt vmcnt(0)" ::: "memory");
          st_cohu(&flg[bid * 32 + w], (unsigned)(s + 1));
        }
      } else {
        if (s < NT - 1) {  // x-projection for t = s+1 -> prebuf[(s+1)&1]
          const f4* px = wsf4 + (XBF >> 2) + (size_t)(s + 1) * 4096 +
                         kg * 32 + bcol;
          f4 bx[32];
          f4 cp = (f4)0.f;
          REP32(LDXM)
          KTXLIST(KT_X)
          const int ppn = (s + 1) & 1;
          #pragma unroll
          for (int e = 0; e < 4; ++e)
            prebuf[ppn * 528 + (j0 + e) * 33 + bcol] = cp[e];
        }
      }
      __syncthreads();
    }
    // ---- final logits aggregation (block 0) ----
    if (bid == 0) {
      if (tid < 64) {
        const unsigned long long* p1 = F1L(tid);
        while (true) {
          unsigned long long v = ld64(p1);
          if ((unsigned)v >= 600u && (unsigned)(v >> 32) >= 600u) break;
        }
      }
      __syncthreads();
      __builtin_amdgcn_sched_barrier(0);
      {
        const int g2 = tid >> 6, pair = tid & 63;
        float v = 0.f;
        for (int blk = g2; blk < 64; blk += 4)
          v += __hip_atomic_load(&ws[PLOG + (size_t)blk * 64 + pair],
                                 __ATOMIC_RELAXED, __HIP_MEMORY_SCOPE_AGENT);
        lgred[tid] = v;
      }
      __syncthreads();
      if (tid < 64) {
        float s2 = bcls[tid >> 5];
        #pragma unroll
        for (int g2 = 0; g2 < 4; ++g2) s2 += lgred[g2 * 64 + tid];
        out[(size_t)(tid & 31) * 2 + (tid >> 5)] = s2;  // logits [B,C]
      }
    }
  } else {
    // ===================== L1 =====================
    for (int t = -1; t < NT; ++t) {
      if (w < 2) {
        if (t >= 0) {
          {  // poll: all flag1 >= t
            const unsigned long long* p1 = F1L(l);
            while (true) {
              unsigned long long v = ld64(p1);
              if ((int)(unsigned)v >= t && (int)(unsigned)(v >> 32) >= t) break;
            }
          }
          __builtin_amdgcn_sched_barrier(0);
          f4 wc0 = *(const f4*)(Wcls + (size_t)t * 1024 + jcol0);
          f4 wc1 = *(const f4*)(Wcls + 524288 + (size_t)t * 1024 + jcol0);
          __builtin_amdgcn_sched_barrier(0);  // pin prefetch OLDER than pipeline
          const f4* ph = wsf4 + (H1R >> 2) + ((t + 1) & 1) * 8192 +
                         kg * 32 + bcol;  // h1(t-1)
          const f4* pl = ph + 4096;
          f4 bh[16], bl[16];
          f4 cr = (f4)0.f;
          PIPE(KT_M)
          const int pp = t & 1;
          float h_[4];
          #pragma unroll
          for (int e = 0; e < 4; ++e)
            h_[e] = tanhf(cr[e] + biasv[e] +
                          prebuf[pp * 528 + (j0 + e) * 33 + bcol]);
          unsigned hi0 = pack_bf16(h_[0], h_[1]), hi1 = pack_bf16(h_[2], h_[3]);
          unsigned lo0 = pack_bf16(h_[0] - bflo(hi0), h_[1] - bfhi(hi0));
          unsigned lo1 = pack_bf16(h_[2] - bflo(hi1), h_[3] - bfhi(hi1));
          u32x2 hp; hp[0] = hi0; hp[1] = hi1;
          u32x2 lp; lp[0] = lo0; lp[1] = lo1;
          unsigned* dp = (unsigned*)ws + H1R + (t & 1) * 32768 +
                         ((jcol0 >> 3) * 32 + bcol) * 4 + ((jcol0 >> 1) & 3);
          STG2(dp, hp);
          STG2(dp + 16384, lp);
          if (t == NT - 1) {
            f4 o; o[0] = h_[0]; o[1] = h_[1]; o[2] = h_[2]; o[3] = h_[3];
            *(f4*)(out + 64 + 32768 + (size_t)bcol * 1024 + jcol0) = o;
          }
          lg0 += h_[0]*wc0[0] + h_[1]*wc0[1] + h_[2]*wc0[2] + h_[3]*wc0[3];
          lg1 += h_[0]*wc1[0] + h_[1]*wc1[1] + h_[2]*wc1[2] + h_[3]*wc1[3];
          asm volatile("s_waitcnt vmcnt(0)" ::: "memory");
          st_cohu(&flg[2048 + (bid - 64) * 32 + w], (unsigned)(t + 1));
        }
      } else {
        if (t < NT - 1) {  // tail: Wih1 x h0(t+1) -> prebuf[(t+1)&1]
          {  // gate: all flag0 >= t+2
            const unsigned long long* p0 = F0L(l);
            const int b0 = t + 2;
            while (true) {
              unsigned long long v = ld64(p0);
              if ((int)(unsigned)v >= b0 && (int)(unsigned)(v >> 32) >= b0) break;
            }
          }
          __builtin_amdgcn_sched_barrier(0);
          const f4* ph = wsf4 + ((t + 1) & 3) * 8192 + kg * 32 + bcol;  // h0(t+1)
          const f4* pl = ph + 4096;
          f4 bh[16], bl[16];
          f4 cp = (f4)0.f;
          PIPE(KT_G)
          const int ppn = (t + 1) & 1;
          #pragma unroll
          for (int e = 0; e < 4; ++e)
            prebuf[ppn * 528 + (j0 + e) * 33 + bcol] = cp[e];
        }
      }
      __syncthreads();
    }
    // ---- logits partials + completion flag ----
    if (w < 2) {
      lg0 += __shfl_xor(lg0, 16); lg0 += __shfl_xor(lg0, 32);
      lg1 += __shfl_xor(lg1, 16); lg1 += __shfl_xor(lg1, 32);
      if (kg == 0) { lgred[bcol] = lg0; lgred[32 + bcol] = lg1; }
    }
    __syncthreads();
    if (tid < 64) {
      st_cohf(&ws[PLOG + (size_t)(bid - 64) * 64 + tid], lgred[tid]);
      asm volatile("s_waitcnt vmcnt(0)" ::: "memory");
    }
    __syncthreads();
    if (tid == 0) {
      st_cohu(&flg[2048 + (bid - 64) * 32 + 0], 600u);
      st_cohu(&flg[2048 + (bid - 64) * 32 + 1], 600u);
    }
  }
}

extern "C" void kernel_launch(void* const* d_in, const int* in_sizes, int n_in,
                              void* d_out, int out_size, void* d_ws, size_t ws_size,
                              hipStream_t stream) {
  const float* x    = (const float*)d_in[0];
  const float* h0   = (const float*)d_in[1];
  const float* Wih0 = (const float*)d_in[2];
  const float* Whh0 = (const float*)d_in[3];
  const float* bih0 = (const float*)d_in[4];
  const float* bhh0 = (const float*)d_in[5];
  const float* Wih1 = (const float*)d_in[6];
  const float* Whh1 = (const float*)d_in[7];
  const float* bih1 = (const float*)d_in[8];
  const float* bhh1 = (const float*)d_in[9];
  const float* Wcls = (const float*)d_in[10];
  const float* bcls = (const float*)d_in[11];
  float* out = (float*)d_out;
  float* ws  = (float*)d_ws;

  hipFuncSetAttribute((const void*)rnn_kernel,
                      hipFuncAttributeMaxDynamicSharedMemorySize, 135296);

  hipLaunchKernelGGL(wconv_kernel, dim3(4096), dim3(128), 0, stream,
                     Whh0, Wih0, Wih1, Whh1, ws);
  hipLaunchKernelGGL(xconv_kernel, dim3(512), dim3(128), 0, stream, x, ws);
  hipLaunchKernelGGL(hinit_kernel, dim3(32), dim3(256), 0, stream, h0, ws);

  void* args[] = { (void*)&bih0, (void*)&bhh0, (void*)&bih1, (void*)&bhh1,
                   (void*)&Wcls, (void*)&bcls, (void*)&out, (void*)&ws };
  hipError_t e = hipLaunchCooperativeKernel((void*)rnn_kernel, dim3(128),
                                            dim3(256), args, 135296, stream);
  if (e != hipSuccess) {
    // Fallback: plain launch. Sync is custom flag-based (no cg); 128 blocks at
    // 1 block/CU on a 256-CU chip are all immediately resident.
    hipLaunchKernelGGL(rnn_kernel, dim3(128), dim3(256), 135296, stream,
                       bih0, bhh0, bih1, bhh1, Wcls, bcls, out, ws);
  }
}